// Round 10
// baseline (33.862 us; speedup 1.0000x reference)
//
#include <hip/hip_runtime.h>

// PatchStd: out = sqrt( boxconv7(x^2) - boxconv7(x)^2 ), uniform 7x7 weight w.
// x: [16, 1, 1024, 1024] fp32, zero padding 3 on each side.
//
// Structure (proven R8, deepened R9->R10): wave-private LDS row-ring filled
// by global_load_lds DMA issued 7 rows ahead (RING=8), consumed under exact
// counted s_waitcnt vmcnt(N) (2 loads/row, 1 store/output, in-order; never
// 0 mid-loop). Threads ds_read their 12-float windows (3x b128), sliding
// horizontal 7-sums, 7-deep h/q ring + vertical running sums. No barriers
// (each wave touches only its own segment).
//
// R9 BUG FIXED HERE: SEGF must be 320, not 288 — the tail DMA writes
// 64 lanes x 4B = floats 256..319 of the slot (wave-uniform base + lane*size,
// ALL lanes write); 288 overflowed 32 floats into the next ring slot.
// LDS = 4 waves * 8 slots * 320 floats * 4B = 40 KB/block.

#define IMG_W 1024
#define IMG_H 1024
#define SH    8             // output rows per block strip
#define TPB   256
#define NR    (SH + 6)      // 14 input rows per strip
#define RING  8
#define SEGF  320           // floats per LDS slot (272 used; 320 = full 64-lane
                            // footprint of the tail DMA — do not shrink)

typedef float v4f __attribute__((ext_vector_type(4)));

#define WAITV(N) asm volatile("s_waitcnt vmcnt(" #N ")" ::: "memory")

__global__ __launch_bounds__(TPB) void patchstd_kernel(
    const float* __restrict__ img, const float* __restrict__ wptr,
    float* __restrict__ out)
{
    __shared__ float lds[4 * RING * SEGF];          // 40 KB

    const int tx   = threadIdx.x;
    const int w_   = tx >> 6;                       // wave id 0..3 (uniform)
    const int lane = tx & 63;
    const int c0   = tx << 2;                       // first of 4 output cols
    const int y0   = blockIdx.y * SH;
    const float* base  = img + (size_t)blockIdx.z * (IMG_W * IMG_H);
    float*       obase = out + (size_t)blockIdx.z * (IMG_W * IMG_H);
    const float w = wptr[0];

    // Wave w_ covers output cols [256w, 256w+256); segment = cols Sw..Sw+271
    // (Sw = 256w-8); thread's 12-float window (c0-4..c0+7) is at segment
    // float index 4*lane+4. Per-lane global cols clamped in-row (clamped
    // lanes land in padding or are zero-patched at consume).
    const int Sw   = 256 * w_ - 8;
    const int colA = min(max(Sw + 4 * lane, 0), IMG_W - 4);   // dwordx4 quad
    const int colB = min(max(Sw + 256 + lane, 0), IMG_W - 1); // dword tail
    const float* gA = base + colA;
    const float* gB = base + colB;
    float* const seg0 = &lds[w_ * (RING * SEGF)];

    // Issue row j's segment DMA into ring slot j&7 (wave-uniform LDS base).
    auto issue = [&](int j) {
        const int rc = min(max(y0 - 3 + j, 0), IMG_H - 1);    // clamped row
        const size_t ro = (size_t)rc * IMG_W;
        float* sl = seg0 + (j & (RING - 1)) * SEGF;
        __builtin_amdgcn_global_load_lds(
            (const __attribute__((address_space(1))) void*)(gA + ro),
            (__attribute__((address_space(3))) void*)sl, 16, 0, 0);
        __builtin_amdgcn_global_load_lds(
            (const __attribute__((address_space(1))) void*)(gB + ro),
            (__attribute__((address_space(3))) void*)(sl + 256), 4, 0, 0);
    };

    // Horizontal 7-sums for 4 output cols from 12 raw values
    // (window for col c0+k = v[k+1..k+7]).
    auto hsum = [&](const float* v, float* h, float* q) {
        float s = v[1]+v[2]+v[3]+v[4]+v[5]+v[6]+v[7];
        h[0] = s;
        s = s - v[1] + v[8];  h[1] = s;
        s = s - v[2] + v[9];  h[2] = s;
        h[3] = s - v[3] + v[10];
        float sq[11];
        #pragma unroll
        for (int i = 1; i <= 10; ++i) sq[i] = v[i] * v[i];
        float t = sq[1]+sq[2]+sq[3]+sq[4]+sq[5]+sq[6]+sq[7];
        q[0] = t;
        t = t - sq[1] + sq[8];  q[1] = t;
        t = t - sq[2] + sq[9];  q[2] = t;
        q[3] = t - sq[3] + sq[10];
    };

    float rh[7][4], rq[7][4];                       // h/q ring (7 rows)
    float vh[4] = {0.f,0.f,0.f,0.f};                // vertical running sums
    float vq[4] = {0.f,0.f,0.f,0.f};

    // 7-deep pipeline fill: rows 0..6 in flight (14 vm-ops).
    issue(0); issue(1); issue(2); issue(3); issue(4); issue(5); issue(6);

    // Full unroll: ring slots, vmcnt immediates, guards all compile-time.
    // vmcnt(N) at iter j = vm-ops younger than row j's 2 loads in issue
    // order (2 loads/row issued up to row min(j+7,13); 1 store per output
    // emitted in iters 6..j-1, each younger than row j's loads for j>=7):
    //   j<=6: rows j+1..j+7 in flight -> N=14
    //   j=7..13: 2*(13-j) loads + (j-6) stores.
    #pragma unroll
    for (int j = 0; j < NR; ++j) {
        if (j + 7 < NR) issue(j + 7);

        if      (j <= 6)  WAITV(14);
        else if (j == 7)  WAITV(13);
        else if (j == 8)  WAITV(12);
        else if (j == 9)  WAITV(11);
        else if (j == 10) WAITV(10);
        else if (j == 11) WAITV(9);
        else if (j == 12) WAITV(8);
        else              WAITV(7);

        // Consume row j from LDS: 3x ds_read_b128.
        const float* seg = seg0 + (j & (RING - 1)) * SEGF;
        const v4f* p = (const v4f*)(seg + 4 * lane + 4);
        v4f A = p[0], B = p[1], C = p[2];
        float v[12] = {A.x,A.y,A.z,A.w, B.x,B.y,B.z,B.w, C.x,C.y,C.z,C.w};
        if (tx == 0)   { v[0]=0.f; v[1]=0.f; v[2]=0.f;  v[3]=0.f;  }
        if (tx == 255) { v[8]=0.f; v[9]=0.f; v[10]=0.f; v[11]=0.f; }

        float h[4], q[4];
        const int R = y0 - 3 + j;
        if (R < 0 || R >= IMG_H) {                  // block-uniform branch
            #pragma unroll
            for (int k = 0; k < 4; ++k) { h[k] = 0.f; q[k] = 0.f; }
        } else {
            hsum(v, h, q);
        }

        if (j < 6) {                                // warm the vertical window
            #pragma unroll
            for (int k = 0; k < 4; ++k) {
                rh[j][k] = h[k]; rq[j][k] = q[k];
                vh[k] += h[k];   vq[k] += q[k];
            }
            if (j == 5) {
                #pragma unroll
                for (int k = 0; k < 4; ++k) { rh[6][k] = 0.f; rq[6][k] = 0.f; }
            }
        } else {                                    // steady state: emit a row
            const int s = j % 7;                    // departing row's slot
            float o[4];
            #pragma unroll
            for (int k = 0; k < 4; ++k) {
                vh[k] += h[k] - rh[s][k];
                vq[k] += q[k] - rq[s][k];
                rh[s][k] = h[k]; rq[s][k] = q[k];
                float mean = w * vh[k];
                float var  = fmaf(w, vq[k], -(mean * mean));
                o[k] = __builtin_amdgcn_sqrtf(fmaxf(var, 0.f));
            }
            *reinterpret_cast<float4*>(obase + (size_t)(y0 + j - 6) * IMG_W + c0) =
                make_float4(o[0], o[1], o[2], o[3]);
        }
    }
}

extern "C" void kernel_launch(void* const* d_in, const int* in_sizes, int n_in,
                              void* d_out, int out_size, void* d_ws, size_t ws_size,
                              hipStream_t stream) {
    const float* img = (const float*)d_in[0];
    const float* wt  = (const float*)d_in[1];
    float* out = (float*)d_out;
    const int batch = in_sizes[0] / (IMG_W * IMG_H);   // 16
    dim3 grid(1, IMG_H / SH, batch);                   // 2048 blocks
    patchstd_kernel<<<grid, dim3(TPB, 1, 1), 0, stream>>>(img, wt, out);
}

// Round 11
// 28.997 us; speedup vs baseline: 1.1678x; 1.1678x over previous
//
#include <hip/hip_runtime.h>

// PatchStd: out = sqrt( boxconv7(x^2) - boxconv7(x)^2 ), uniform 7x7 weight w.
// x: [16, 1, 1024, 1024] fp32, zero padding 3 on each side.
//
// Structure = R8's proven staging (wave-private LDS row-ring, RING=4, DMA
// issued 3 rows ahead via global_load_lds, exact counted s_waitcnt vmcnt —
// R10 proved depth>3 adds nothing) with SH=16: input rows per output row
// 1.75 -> 1.375 (-21% staging+hsum work), and the whole grid (1024 blocks,
// 4/CU, 20KB LDS each) is co-resident — zero block turnover.
// Consume: 3x ds_read_b128 -> sliding horizontal 7-sums -> 7-deep h/q ring
// + vertical running sums. No barriers (wave-private segments).
// SEGF=320 is the full 64-lane footprint of the tail DMA (R9 lesson).

#define IMG_W 1024
#define IMG_H 1024
#define SH    16            // output rows per block strip
#define TPB   256
#define NR    (SH + 6)      // 22 input rows per strip
#define RING  4
#define SEGF  320           // floats per LDS slot (272 used; 320 = DMA footprint)

typedef float v4f __attribute__((ext_vector_type(4)));

#define WAITV(N) asm volatile("s_waitcnt vmcnt(" #N ")" ::: "memory")

__global__ __launch_bounds__(TPB) void patchstd_kernel(
    const float* __restrict__ img, const float* __restrict__ wptr,
    float* __restrict__ out)
{
    __shared__ float lds[4 * RING * SEGF];          // 20 KB

    const int tx   = threadIdx.x;
    const int w_   = tx >> 6;                       // wave id 0..3 (uniform)
    const int lane = tx & 63;
    const int c0   = tx << 2;                       // first of 4 output cols
    const int y0   = blockIdx.y * SH;
    const float* base  = img + (size_t)blockIdx.z * (IMG_W * IMG_H);
    float*       obase = out + (size_t)blockIdx.z * (IMG_W * IMG_H);
    const float w = wptr[0];

    // Wave w_ covers output cols [256w, 256w+256); segment = cols Sw..Sw+271
    // (Sw = 256w-8); thread's 12-float window (c0-4..c0+7) is at segment
    // float index 4*lane+4. Per-lane global cols clamped in-row (clamped
    // lanes land in padding or are zero-patched at consume).
    const int Sw   = 256 * w_ - 8;
    const int colA = min(max(Sw + 4 * lane, 0), IMG_W - 4);   // dwordx4 quad
    const int colB = min(max(Sw + 256 + lane, 0), IMG_W - 1); // dword tail
    const float* gA = base + colA;
    const float* gB = base + colB;
    float* const seg0 = &lds[w_ * (RING * SEGF)];

    // Issue row j's segment DMA into ring slot j&3 (wave-uniform LDS base).
    auto issue = [&](int j) {
        const int rc = min(max(y0 - 3 + j, 0), IMG_H - 1);    // clamped row
        const size_t ro = (size_t)rc * IMG_W;
        float* sl = seg0 + (j & (RING - 1)) * SEGF;
        __builtin_amdgcn_global_load_lds(
            (const __attribute__((address_space(1))) void*)(gA + ro),
            (__attribute__((address_space(3))) void*)sl, 16, 0, 0);
        __builtin_amdgcn_global_load_lds(
            (const __attribute__((address_space(1))) void*)(gB + ro),
            (__attribute__((address_space(3))) void*)(sl + 256), 4, 0, 0);
    };

    // Horizontal 7-sums for 4 output cols from 12 raw values
    // (window for col c0+k = v[k+1..k+7]).
    auto hsum = [&](const float* v, float* h, float* q) {
        float s = v[1]+v[2]+v[3]+v[4]+v[5]+v[6]+v[7];
        h[0] = s;
        s = s - v[1] + v[8];  h[1] = s;
        s = s - v[2] + v[9];  h[2] = s;
        h[3] = s - v[3] + v[10];
        float sq[11];
        #pragma unroll
        for (int i = 1; i <= 10; ++i) sq[i] = v[i] * v[i];
        float t = sq[1]+sq[2]+sq[3]+sq[4]+sq[5]+sq[6]+sq[7];
        q[0] = t;
        t = t - sq[1] + sq[8];  q[1] = t;
        t = t - sq[2] + sq[9];  q[2] = t;
        q[3] = t - sq[3] + sq[10];
    };

    float rh[7][4], rq[7][4];                       // h/q ring (7 rows)
    float vh[4] = {0.f,0.f,0.f,0.f};                // vertical running sums
    float vq[4] = {0.f,0.f,0.f,0.f};

    issue(0); issue(1); issue(2);                   // 3-deep pipeline fill

    // Full unroll: ring slots, vmcnt immediates, guards all compile-time.
    // vmcnt(N) at iter j = vm-ops younger than row j's 2 loads, issue order
    // (2 loads/row for rows j+1..min(j+3,21); stores from iters
    // [max(6,j-3), j-1], 1 each). Validated against R8's passing table:
    //   j<=6: 6 | j=7: 7 | j=8: 8 | j=9..18: 9 | j=19: 7 | j=20: 5 | j=21: 3.
    #pragma unroll
    for (int j = 0; j < NR; ++j) {
        if (j + 3 < NR) issue(j + 3);

        if      (j <= 6)  WAITV(6);
        else if (j == 7)  WAITV(7);
        else if (j == 8)  WAITV(8);
        else if (j <= 18) WAITV(9);
        else if (j == 19) WAITV(7);
        else if (j == 20) WAITV(5);
        else              WAITV(3);

        // Consume row j from LDS: 3x ds_read_b128.
        const float* seg = seg0 + (j & (RING - 1)) * SEGF;
        const v4f* p = (const v4f*)(seg + 4 * lane + 4);
        v4f A = p[0], B = p[1], C = p[2];
        float v[12] = {A.x,A.y,A.z,A.w, B.x,B.y,B.z,B.w, C.x,C.y,C.z,C.w};
        if (tx == 0)   { v[0]=0.f; v[1]=0.f; v[2]=0.f;  v[3]=0.f;  }
        if (tx == 255) { v[8]=0.f; v[9]=0.f; v[10]=0.f; v[11]=0.f; }

        float h[4], q[4];
        const int R = y0 - 3 + j;
        if (R < 0 || R >= IMG_H) {                  // block-uniform branch
            #pragma unroll
            for (int k = 0; k < 4; ++k) { h[k] = 0.f; q[k] = 0.f; }
        } else {
            hsum(v, h, q);
        }

        if (j < 6) {                                // warm the vertical window
            #pragma unroll
            for (int k = 0; k < 4; ++k) {
                rh[j][k] = h[k]; rq[j][k] = q[k];
                vh[k] += h[k];   vq[k] += q[k];
            }
            if (j == 5) {
                #pragma unroll
                for (int k = 0; k < 4; ++k) { rh[6][k] = 0.f; rq[6][k] = 0.f; }
            }
        } else {                                    // steady state: emit a row
            const int s = j % 7;                    // departing row's slot
            float o[4];
            #pragma unroll
            for (int k = 0; k < 4; ++k) {
                vh[k] += h[k] - rh[s][k];
                vq[k] += q[k] - rq[s][k];
                rh[s][k] = h[k]; rq[s][k] = q[k];
                float mean = w * vh[k];
                float var  = fmaf(w, vq[k], -(mean * mean));
                o[k] = __builtin_amdgcn_sqrtf(fmaxf(var, 0.f));
            }
            *reinterpret_cast<float4*>(obase + (size_t)(y0 + j - 6) * IMG_W + c0) =
                make_float4(o[0], o[1], o[2], o[3]);
        }
    }
}

extern "C" void kernel_launch(void* const* d_in, const int* in_sizes, int n_in,
                              void* d_out, int out_size, void* d_ws, size_t ws_size,
                              hipStream_t stream) {
    const float* img = (const float*)d_in[0];
    const float* wt  = (const float*)d_in[1];
    float* out = (float*)d_out;
    const int batch = in_sizes[0] / (IMG_W * IMG_H);   // 16
    dim3 grid(1, IMG_H / SH, batch);                   // 1024 blocks, all co-resident
    patchstd_kernel<<<grid, dim3(TPB, 1, 1), 0, stream>>>(img, wt, out);
}